// Round 2
// baseline (226.935 us; speedup 1.0000x reference)
//
#include <hip/hip_runtime.h>
#include <climits>

// R12: MEASUREMENT ROUND (deliberate, idempotent). R11 fused kernel is kept
// byte-identical; probe lanes additionally persist bounds to d_ws; a second
// emit-only kernel re-reads bounds and rewrites the IDENTICAL output.
// dur_us delta vs R11 (215.5) = true standalone cost of one 128-MiB emit
// pass. Disambiguates: World A (emit ~20-28us, healthy stores -> total is
// harness-poison-dominated -> roofline) vs World B (emit >=45us, the prior
// session's 2.4 TB/s store pathology is real -> it becomes the target).
// Output values unchanged -> absmax must stay 0.0.

#define BLOCK 256
#define ROWS 4

typedef float nfloat4 __attribute__((ext_vector_type(4)));  // native vec4

__device__ __forceinline__ float sigmoid10(float x) {
    return 1.0f / (1.0f + expf(-10.0f * x));  // matches reference numerics
}
__device__ __forceinline__ float fdiff(float p, float tl, float tr) {
    return sigmoid10(p - tl) - sigmoid10(p - tr);
}

// exact per-row bounds: [lo, hi] inclusive index interval where output is 1
__device__ __forceinline__ int2 probe_row(const float* __restrict__ mrow,
                                          float tv, float lv, int Llen) {
    int blo = -1, bhi = Llen;
    #pragma unroll 1
    while (bhi - blo > 1) {
        const int mid = (blo + bhi) >> 1;   // always in [0, Llen-1]
        if (mrow[mid] > 0.5f) blo = mid; else bhi = mid;
    }
    const int len = bhi;

    int lo = 1, hi = 0;                     // empty-interval default
    if (len > 0) {
        const float leftf  = -1.0f;
        const float rightf = (float)len;
        const float sl = 0.5f * (float)len;
        const float leff = (lv <= sl) ? sl : lv;
        float tl0 = tv - leff;
        float t_left = (tl0 >= leftf) ? tl0 : 0.0f;
        if (t_left == 0.0f) t_left = leftf;
        float tr0 = tv + leff;
        float t_right = (tr0 <= rightf) ? tr0 : 0.0f;
        if (t_right == 0.0f) t_right = rightf;

        const float c = expf(-10.0f * (t_right - t_left));
        const float b = 1.0f - 3.0f * c;
        const float disc = b * b - 4.0f * c;
        if (b > 0.0f && disc >= 0.0f) {
            const float xp = 0.5f * (b + sqrtf(disc));
            const float p_lo = t_left - 0.1f * logf(xp);
            const float p_hi = (t_left + t_right) - p_lo;
            lo = (int)ceilf(p_lo);
            hi = (int)floorf(p_hi);
            #pragma unroll 1
            for (int k = 0; k < 4 && fdiff((float)(lo - 1), t_left, t_right) >= 0.5f; ++k) --lo;
            #pragma unroll 1
            for (int k = 0; k < 4 && fdiff((float)lo, t_left, t_right) < 0.5f; ++k) ++lo;
            #pragma unroll 1
            for (int k = 0; k < 4 && fdiff((float)(hi + 1), t_left, t_right) >= 0.5f; ++k) ++hi;
            #pragma unroll 1
            for (int k = 0; k < 4 && fdiff((float)hi, t_left, t_right) < 0.5f; ++k) --hi;
        }
        lo = max(lo, 0);
        hi = min(hi, len - 1);
    }
    return make_int2(lo, hi);
}

__device__ __forceinline__ void emit_rows(const int2* __restrict__ sb,
                                          float* __restrict__ out,
                                          int row0, int nrows, int Llen, int tid) {
    if ((Llen & 3) == 0) {
        const int nv4 = Llen >> 2;
        nfloat4* ob = (nfloat4*)out + (size_t)row0 * nv4;
        #pragma unroll 1
        for (int r = 0; r < nrows; ++r) {
            const int2 bnd = sb[r];
            nfloat4* orow = ob + (size_t)r * nv4;
            for (int j = tid; j < nv4; j += BLOCK) {
                const int e = j << 2;
                nfloat4 o;
                o.x = (e     >= bnd.x && e     <= bnd.y) ? 1.0f : 0.0f;
                o.y = (e + 1 >= bnd.x && e + 1 <= bnd.y) ? 1.0f : 0.0f;
                o.z = (e + 2 >= bnd.x && e + 2 <= bnd.y) ? 1.0f : 0.0f;
                o.w = (e + 3 >= bnd.x && e + 3 <= bnd.y) ? 1.0f : 0.0f;
                orow[j] = o;
            }
        }
    } else {
        #pragma unroll 1
        for (int r = 0; r < nrows; ++r) {
            const int2 bnd = sb[r];
            float* orow = out + (size_t)(row0 + r) * Llen;
            for (int j = tid; j < Llen; j += BLOCK)
                orow[j] = (j >= bnd.x && j <= bnd.y) ? 1.0f : 0.0f;
        }
    }
}

__global__ __launch_bounds__(BLOCK) void fused_kernel(
    const float* __restrict__ t, const float* __restrict__ l,
    const float* __restrict__ mask, float* __restrict__ out,
    int2* __restrict__ ws, int B, int Llen) {
    __shared__ int2 sb[ROWS];
    const int row0 = blockIdx.x * ROWS;
    const int tid = threadIdx.x;

    if (tid < ROWS) {
        const int row = row0 + tid;
        int2 r = make_int2(1, 0);
        if (row < B)
            r = probe_row(mask + (size_t)row * Llen, t[row], l[row], Llen);
        sb[tid] = r;
        if (row < B) ws[row] = r;           // persist for the replay kernel
    }
    __syncthreads();

    const int nrows = min(ROWS, B - row0);
    emit_rows(sb, out, row0, nrows, Llen, tid);
}

// idempotent replay: structurally identical emit phase, bounds from ws.
// Its marginal dur_us vs R11 IS the standalone emit cost.
__global__ __launch_bounds__(BLOCK) void emit_replay_kernel(
    const int2* __restrict__ ws, float* __restrict__ out, int B, int Llen) {
    __shared__ int2 sb[ROWS];
    const int row0 = blockIdx.x * ROWS;
    const int tid = threadIdx.x;
    if (tid < ROWS) {
        const int row = row0 + tid;
        sb[tid] = (row < B) ? ws[row] : make_int2(1, 0);
    }
    __syncthreads();
    const int nrows = min(ROWS, B - row0);
    emit_rows(sb, out, row0, nrows, Llen, tid);
}

extern "C" void kernel_launch(void* const* d_in, const int* in_sizes, int n_in,
                              void* d_out, int out_size, void* d_ws, size_t ws_size,
                              hipStream_t stream) {
    const float* t    = (const float*)d_in[0];
    const float* l    = (const float*)d_in[1];
    const float* mask = (const float*)d_in[2];
    float* out = (float*)d_out;
    int2* ws = (int2*)d_ws;

    const int B = in_sizes[0];
    const int Llen = in_sizes[2] / B;

    const int blocks = (B + ROWS - 1) / ROWS;   // 2048 @ B=8192
    fused_kernel<<<blocks, BLOCK, 0, stream>>>(t, l, mask, out, ws, B, Llen);
    emit_replay_kernel<<<blocks, BLOCK, 0, stream>>>(ws, out, B, Llen);
}

// Round 3
// 226.692 us; speedup vs baseline: 1.0011x; 1.0011x over previous
//
#include <hip/hip_runtime.h>
#include <climits>

// R13: probe latency-chain cut. R12 measured a standalone emit pass at
// +11.4us marginal (L3-warm) -> store path is healthy (World A); the 219us
// headline is ~160us of harness 512-MiB poison fills + our ~27us kernel.
// Remaining controllable slack: the probe's 13 dependent-miss binary-search
// chain (~5us) gating every block's emit via __syncthreads. Replace with a
// 2-round wave-cooperative ballot search: wave w owns row w; round 1 samples
// mask[lane*64] (one parallel miss) -> ballot localizes len to a 64-segment;
// round 2 reads the segment coalesced -> popcount gives len exactly.
// 2 dependent rounds instead of 13; 4 rows probed by 4 parallel waves.
// Analytic bounds math unchanged (absmax-0.0 path since R2).
// Pre-commit: if dur_us >= 214 (noise band of 215.5), declare ROOFLINE.

#define BLOCK 256
#define ROWS 4

typedef float nfloat4 __attribute__((ext_vector_type(4)));  // native vec4

__device__ __forceinline__ float sigmoid10(float x) {
    return 1.0f / (1.0f + expf(-10.0f * x));  // matches reference numerics
}
__device__ __forceinline__ float fdiff(float p, float tl, float tr) {
    return sigmoid10(p - tl) - sigmoid10(p - tr);
}

// exact bounds from len (prefix mask: left=-1, right=len, sum=len)
__device__ __forceinline__ int2 bounds_from_len(int len, float tv, float lv) {
    int lo = 1, hi = 0;                     // empty-interval default
    if (len > 0) {
        const float leftf  = -1.0f;
        const float rightf = (float)len;
        const float sl = 0.5f * (float)len;
        const float leff = (lv <= sl) ? sl : lv;
        float tl0 = tv - leff;
        float t_left = (tl0 >= leftf) ? tl0 : 0.0f;
        if (t_left == 0.0f) t_left = leftf;
        float tr0 = tv + leff;
        float t_right = (tr0 <= rightf) ? tr0 : 0.0f;
        if (t_right == 0.0f) t_right = rightf;

        const float c = expf(-10.0f * (t_right - t_left));
        const float b = 1.0f - 3.0f * c;
        const float disc = b * b - 4.0f * c;
        if (b > 0.0f && disc >= 0.0f) {
            const float xp = 0.5f * (b + sqrtf(disc));
            const float p_lo = t_left - 0.1f * logf(xp);
            const float p_hi = (t_left + t_right) - p_lo;
            lo = (int)ceilf(p_lo);
            hi = (int)floorf(p_hi);
            // refine to exact fp32 classification boundaries (proven path)
            #pragma unroll 1
            for (int k = 0; k < 4 && fdiff((float)(lo - 1), t_left, t_right) >= 0.5f; ++k) --lo;
            #pragma unroll 1
            for (int k = 0; k < 4 && fdiff((float)lo, t_left, t_right) < 0.5f; ++k) ++lo;
            #pragma unroll 1
            for (int k = 0; k < 4 && fdiff((float)(hi + 1), t_left, t_right) >= 0.5f; ++k) ++hi;
            #pragma unroll 1
            for (int k = 0; k < 4 && fdiff((float)hi, t_left, t_right) < 0.5f; ++k) --hi;
        }
        lo = max(lo, 0);                    // fold "* mask" (prefix)
        hi = min(hi, len - 1);
    }
    return make_int2(lo, hi);
}

__global__ __launch_bounds__(BLOCK) void fused_kernel(
    const float* __restrict__ t, const float* __restrict__ l,
    const float* __restrict__ mask, float* __restrict__ out,
    int B, int Llen) {
    __shared__ int2 sb[ROWS];
    const int row0 = blockIdx.x * ROWS;
    const int tid = threadIdx.x;
    const int wv = tid >> 6;
    const int lane = tid & 63;

    // wave wv probes row row0+wv: 2-round ballot search for len
    if (wv < ROWS) {                         // wave-uniform
        const int row = row0 + wv;
        if (row < B) {                       // wave-uniform
            const float* mrow = mask + (size_t)row * Llen;
            int len;
            if (Llen <= 64 * 64) {
                const int stride = (Llen + 63) >> 6;      // 64 @ L=4096
                const int i1 = lane * stride;
                const bool p1 = (i1 < Llen) && (mrow[i1] > 0.5f);
                const unsigned long long b1 = __ballot(p1);
                const int s = __popcll(b1);               // ceil(len/stride)
                if (s == 0) {
                    len = 0;
                } else {
                    const int base = (s - 1) * stride;
                    const int i2 = base + lane;           // stride<=64 lanes cover it
                    const bool p2 = (i2 < Llen) && (mrow[i2] > 0.5f);
                    len = base + __popcll(__ballot(p2));
                }
            } else {
                // generic fallback: per-lane binary search (all lanes same result)
                int blo = -1, bhi = Llen;
                #pragma unroll 1
                while (bhi - blo > 1) {
                    const int mid = (blo + bhi) >> 1;
                    if (mrow[mid] > 0.5f) blo = mid; else bhi = mid;
                }
                len = bhi;
            }
            if (lane == 0)
                sb[wv] = bounds_from_len(len, t[row], l[row]);
        } else if (lane == 0) {
            sb[wv] = make_int2(1, 0);
        }
    }
    __syncthreads();

    const int nrows = min(ROWS, B - row0);
    if ((Llen & 3) == 0) {
        const int nv4 = Llen >> 2;
        nfloat4* ob = (nfloat4*)out + (size_t)row0 * nv4;
        #pragma unroll 1
        for (int r = 0; r < nrows; ++r) {
            const int2 bnd = sb[r];          // wave-uniform LDS broadcast
            nfloat4* orow = ob + (size_t)r * nv4;
            for (int j = tid; j < nv4; j += BLOCK) {
                const int e = j << 2;
                nfloat4 o;
                o.x = (e     >= bnd.x && e     <= bnd.y) ? 1.0f : 0.0f;
                o.y = (e + 1 >= bnd.x && e + 1 <= bnd.y) ? 1.0f : 0.0f;
                o.z = (e + 2 >= bnd.x && e + 2 <= bnd.y) ? 1.0f : 0.0f;
                o.w = (e + 3 >= bnd.x && e + 3 <= bnd.y) ? 1.0f : 0.0f;
                orow[j] = o;                 // plain store: fill-proven pattern
            }
        }
    } else {
        #pragma unroll 1
        for (int r = 0; r < nrows; ++r) {
            const int2 bnd = sb[r];
            float* orow = out + (size_t)(row0 + r) * Llen;
            for (int j = tid; j < Llen; j += BLOCK)
                orow[j] = (j >= bnd.x && j <= bnd.y) ? 1.0f : 0.0f;
        }
    }
}

extern "C" void kernel_launch(void* const* d_in, const int* in_sizes, int n_in,
                              void* d_out, int out_size, void* d_ws, size_t ws_size,
                              hipStream_t stream) {
    const float* t    = (const float*)d_in[0];
    const float* l    = (const float*)d_in[1];
    const float* mask = (const float*)d_in[2];
    float* out = (float*)d_out;
    (void)d_ws; (void)ws_size;

    const int B = in_sizes[0];
    const int Llen = in_sizes[2] / B;

    const int blocks = (B + ROWS - 1) / ROWS;   // 2048 @ B=8192
    fused_kernel<<<blocks, BLOCK, 0, stream>>>(t, l, mask, out, B, Llen);
}

// Round 4
// 216.114 us; speedup vs baseline: 1.0501x; 1.0489x over previous
//
#include <hip/hip_runtime.h>
#include <climits>

// R14: REVERT to R11 (best measured: 215.5us). R13's ballot probe regressed
// +11.2us with a clear mechanism: it traded 832B/row of latency-hidden
// binary-search fetch (overlapped across 8 blocks/CU) for ~4KB/row of
// SCATTERED 64B-granule fetches (one line per 256B stride) that contend
// with the 128-MiB store stream at poor DRAM efficiency -> ~+10us, matching
// the measurement. The probe was never on the critical path; the binary
// search stays.
// Kernel budget: ~19us write floor (128MiB @ fill-proven 6.7TB/s) + ~1us
// probe fetch; remaining ~190us of dur_us is harness poison fills (80us
// 512-MiB fills visible in top-5) + gaps. Controllable slack < noise.

#define BLOCK 256
#define ROWS 4

typedef float nfloat4 __attribute__((ext_vector_type(4)));  // native vec4

__device__ __forceinline__ float sigmoid10(float x) {
    return 1.0f / (1.0f + expf(-10.0f * x));  // matches reference numerics
}
__device__ __forceinline__ float fdiff(float p, float tl, float tr) {
    return sigmoid10(p - tl) - sigmoid10(p - tr);
}

// exact per-row bounds: [lo, hi] inclusive index interval where output is 1
__device__ __forceinline__ int2 probe_row(const float* __restrict__ mrow,
                                          float tv, float lv, int Llen) {
    // binary search for len = first zero (contiguous valid-prefix mask)
    int blo = -1, bhi = Llen;
    #pragma unroll 1
    while (bhi - blo > 1) {
        const int mid = (blo + bhi) >> 1;   // always in [0, Llen-1]
        if (mrow[mid] > 0.5f) blo = mid; else bhi = mid;
    }
    const int len = bhi;

    int lo = 1, hi = 0;                     // empty-interval default
    if (len > 0) {
        // reference scalar path (prefix mask: left=-1, right=len, sum=len)
        const float leftf  = -1.0f;
        const float rightf = (float)len;
        const float sl = 0.5f * (float)len;
        const float leff = (lv <= sl) ? sl : lv;
        float tl0 = tv - leff;
        float t_left = (tl0 >= leftf) ? tl0 : 0.0f;
        if (t_left == 0.0f) t_left = leftf;
        float tr0 = tv + leff;
        float t_right = (tr0 <= rightf) ? tr0 : 0.0f;
        if (t_right == 0.0f) t_right = rightf;

        // analytic sigmoid-difference >= 0.5 interval
        const float c = expf(-10.0f * (t_right - t_left));
        const float b = 1.0f - 3.0f * c;
        const float disc = b * b - 4.0f * c;
        if (b > 0.0f && disc >= 0.0f) {
            const float xp = 0.5f * (b + sqrtf(disc));
            const float p_lo = t_left - 0.1f * logf(xp);
            const float p_hi = (t_left + t_right) - p_lo;
            lo = (int)ceilf(p_lo);
            hi = (int)floorf(p_hi);
            // refine to exact fp32 classification boundaries (proven path)
            #pragma unroll 1
            for (int k = 0; k < 4 && fdiff((float)(lo - 1), t_left, t_right) >= 0.5f; ++k) --lo;
            #pragma unroll 1
            for (int k = 0; k < 4 && fdiff((float)lo, t_left, t_right) < 0.5f; ++k) ++lo;
            #pragma unroll 1
            for (int k = 0; k < 4 && fdiff((float)(hi + 1), t_left, t_right) >= 0.5f; ++k) ++hi;
            #pragma unroll 1
            for (int k = 0; k < 4 && fdiff((float)hi, t_left, t_right) < 0.5f; ++k) --hi;
        }
        lo = max(lo, 0);                    // fold "* mask" (prefix)
        hi = min(hi, len - 1);
    }
    return make_int2(lo, hi);
}

__global__ __launch_bounds__(BLOCK) void fused_kernel(
    const float* __restrict__ t, const float* __restrict__ l,
    const float* __restrict__ mask, float* __restrict__ out,
    int B, int Llen) {
    __shared__ int2 sb[ROWS];
    const int row0 = blockIdx.x * ROWS;
    const int tid = threadIdx.x;

    // lanes 0..3 of wave 0: 4 binary searches in parallel (one latency chain,
    // hidden under other co-resident blocks' emit waves)
    if (tid < ROWS) {
        const int row = row0 + tid;
        int2 r = make_int2(1, 0);
        if (row < B)
            r = probe_row(mask + (size_t)row * Llen, t[row], l[row], Llen);
        sb[tid] = r;
    }
    __syncthreads();

    const int nrows = min(ROWS, B - row0);
    if ((Llen & 3) == 0) {
        const int nv4 = Llen >> 2;
        nfloat4* ob = (nfloat4*)out + (size_t)row0 * nv4;
        #pragma unroll 1
        for (int r = 0; r < nrows; ++r) {
            const int2 bnd = sb[r];          // wave-uniform LDS broadcast
            nfloat4* orow = ob + (size_t)r * nv4;
            for (int j = tid; j < nv4; j += BLOCK) {
                const int e = j << 2;
                nfloat4 o;
                o.x = (e     >= bnd.x && e     <= bnd.y) ? 1.0f : 0.0f;
                o.y = (e + 1 >= bnd.x && e + 1 <= bnd.y) ? 1.0f : 0.0f;
                o.z = (e + 2 >= bnd.x && e + 2 <= bnd.y) ? 1.0f : 0.0f;
                o.w = (e + 3 >= bnd.x && e + 3 <= bnd.y) ? 1.0f : 0.0f;
                orow[j] = o;                 // plain store: fill-proven pattern
            }
        }
    } else {
        // generic fallback (not hit at L=4096)
        #pragma unroll 1
        for (int r = 0; r < nrows; ++r) {
            const int2 bnd = sb[r];
            float* orow = out + (size_t)(row0 + r) * Llen;
            for (int j = tid; j < Llen; j += BLOCK)
                orow[j] = (j >= bnd.x && j <= bnd.y) ? 1.0f : 0.0f;
        }
    }
}

extern "C" void kernel_launch(void* const* d_in, const int* in_sizes, int n_in,
                              void* d_out, int out_size, void* d_ws, size_t ws_size,
                              hipStream_t stream) {
    const float* t    = (const float*)d_in[0];
    const float* l    = (const float*)d_in[1];
    const float* mask = (const float*)d_in[2];
    float* out = (float*)d_out;
    (void)d_ws; (void)ws_size;

    const int B = in_sizes[0];
    const int Llen = in_sizes[2] / B;

    const int blocks = (B + ROWS - 1) / ROWS;   // 2048 @ B=8192 -> 32 waves/CU
    fused_kernel<<<blocks, BLOCK, 0, stream>>>(t, l, mask, out, B, Llen);
}